// Round 5
// baseline (446.543 us; speedup 1.0000x reference)
//
#include <hip/hip_runtime.h>

// pose3d_future loss, round 5: small-tile async-DMA pipeline with real TLP.
// R4 post-mortem: structure was right but 3 single-wave blocks/CU left ~105
// sunk scalar ds_reads/thread latency-exposed (~12.6K cy/tile == measured).
// R5: TILE=16 samples per 64-thread block, 4 threads per sample (joint ranges
// 6/5/5/5 -- output is a pure sum, so lanes don't need sample ownership).
// LDS = 2 x 6720 B = 13.4 KB/block -> ~11 blocks(waves)/CU: LDS latency and
// vmcnt stalls now hide across waves. DMA: 7 x global_load_lds(16B) per tile,
// double-buffered, no barriers (single wave), manual vmcnt(7) overlap.

namespace {

constexpr float F_    = 525.0f;
constexpr float CX_   = 320.0f;
constexpr float CY_   = 240.0f;
constexpr float WPROJ = 0.33f / 42.0f;   // W_PROJ / (2*J)
constexpr float WBONE = 0.5f  / 20.0f;   // W_BONE / (J-1)
constexpr int   NT    = 64;              // one wave per block
constexpr int   TILE  = 16;              // samples per tile
constexpr int   PF4   = TILE * 63 / 4;   // 252 float4 of pose per tile
constexpr int   EF4   = TILE * 42 / 4;   // 168 float4 of est per tile
constexpr int   TF4   = PF4 + EF4;       // 420 float4 = 6720 B per tile
constexpr int   RFULL = TF4 / NT;        // 6 full DMA rounds
constexpr int   REM   = TF4 - RFULL*NT;  // 36-lane remainder round
constexpr int   DMA_N = RFULL + 1;       // 7 vm events per tile
constexpr int   NBLK  = 2816;            // ~11 single-wave blocks per CU

// gfx9/CDNA s_waitcnt imm: vmcnt[3:0]=b[3:0], vmcnt[5:4]=b[15:14],
// expcnt=b[6:4] (7=no wait), lgkmcnt[11:8] (15=no wait).
constexpr int wcnt(int vm, int lgkm) {
    return (vm & 0xF) | ((vm >> 4) << 14) | (0x7 << 4) | ((lgkm & 0xF) << 8);
}

__device__ __forceinline__ long lmin(long a, long b) { return a < b ? a : b; }

__global__ __launch_bounds__(NT)
void pose_loss_kernel(const float* __restrict__ pose,   // [B,3,21]
                      const float* __restrict__ est,    // [B,2,21]
                      const float* __restrict__ bl,     // [20]
                      const float* __restrict__ Rm,     // [3,3]
                      const float* __restrict__ Cd,     // [3,1]
                      float* __restrict__ out,
                      int B)
{
    __shared__ float smf[2 * TF4 * 4];   // 13440 B (2 buffers x 1680 floats)

    const int tid = threadIdx.x;
    const float4* pose4 = (const float4*)pose;
    const float4* est4  = (const float4*)est;
    const long pmax = (long)B * 63 / 4 - 1;   // B%4==0 => exact coverage
    const long emax = (long)B * 42 / 4 - 1;
    const long ntiles = ((long)B + TILE - 1) / TILE;

    // ---- uniform camera params: M = K @ R^T; fold C into the row offsets ----
    const float r0 = Rm[0], r1 = Rm[1], r2 = Rm[2];
    const float r3 = Rm[3], r4 = Rm[4], r5 = Rm[5];
    const float r6 = Rm[6], r7 = Rm[7], r8 = Rm[8];
    const float m00 = F_ * r0 + CX_ * r2;
    const float m01 = F_ * r3 + CX_ * r5;
    const float m02 = F_ * r6 + CX_ * r8;
    const float m10 = F_ * r1 + CY_ * r2;
    const float m11 = F_ * r4 + CY_ * r5;
    const float m12 = F_ * r7 + CY_ * r8;
    const float m20 = r2, m21 = r5, m22 = r8;
    const float c0 = Cd[0], c1 = Cd[1], c2 = Cd[2];
    const float t0 = m00 * c0 + m01 * c1 + m02 * c2;   // q0 offset
    const float t1 = m10 * c0 + m11 * c1 + m12 * c2;
    const float t2 = m20 * c0 + m21 * c1 + m22 * c2;

    // ---- work split: thread = (sample-in-tile, joint-quarter) ----
    const int  s_loc   = tid & 15;
    const int  q       = tid >> 4;
    const int  jstart  = (q == 0) ? 0 : (1 + 5 * q);   // 0,6,11,16
    const int  cntq    = (q == 0) ? 6 : 5;
    float blk[6];
    #pragma unroll
    for (int k = 0; k < 6; ++k) {       // bone target for joint jstart+k
        int bi = jstart + k - 1;
        bi = bi < 0 ? 0 : (bi > 19 ? 19 : bi);
        blk[k] = bl[bi];                // hoisted: L1-hot, once per block
    }

    // ---- async DMA of one 16-sample tile into LDS buffer `buf` ----
    auto dma = [&](long T, int buf) {
        const long pb = T * PF4;
        const long eb = T * EF4 - PF4;            // est f4 = eb + f
        float4* dst = (float4*)&smf[buf * TF4 * 4];
        #pragma unroll
        for (int r = 0; r < RFULL; ++r) {
            const int f = r * NT + tid;
            const float4* g = (f < PF4) ? (pose4 + lmin(pb + f, pmax))
                                        : (est4  + lmin(eb + f, emax));
            __builtin_amdgcn_global_load_lds(
                (const __attribute__((address_space(1))) void*)g,
                (__attribute__((address_space(3))) void*)(dst + r * NT),
                16, 0, 0);
        }
        if (tid < REM) {                          // f = 384..419, all est
            const long gi = lmin(eb + RFULL * NT + tid, emax);
            __builtin_amdgcn_global_load_lds(
                (const __attribute__((address_space(1))) void*)(est4 + gi),
                (__attribute__((address_space(3))) void*)(dst + RFULL * NT),
                16, 0, 0);
        }
    };

    float accP = 0.0f, accB = 0.0f;
    long T = blockIdx.x;
    if (T < ntiles) dma(T, 0);

    int i = 0;
    while (T < ntiles) {
        const long Tn = T + gridDim.x;
        __asm__ __volatile__("" ::: "memory");
        __builtin_amdgcn_s_waitcnt(wcnt(63, 0));   // my ds_reads retired
        if (Tn < ntiles) {
            dma(Tn, (i + 1) & 1);                          // +7 in flight
            __builtin_amdgcn_s_waitcnt(wcnt(DMA_N, 15));   // tile T landed
        } else {
            __builtin_amdgcn_s_waitcnt(wcnt(0, 15));       // tail drain
        }
        __asm__ __volatile__("" ::: "memory");

        // ---- compute tile T from LDS buffer i&1 ----
        const float* sm = &smf[(i & 1) * TF4 * 4];
        const int pb = s_loc * 63;                 // x0..20 y0..20 z0..20
        const int eb = TILE * 63 + s_loc * 42;     // u0..20 v0..20
        const bool valid = (T * TILE + s_loc) < (long)B;

        const int jp = (jstart > 0) ? jstart - 1 : 0;   // prev joint (q0 masked)
        float pvx = sm[pb + jp], pvy = sm[pb + 21 + jp], pvz = sm[pb + 42 + jp];
        #pragma unroll
        for (int k = 0; k < 6; ++k) {
            const int j = jstart + k;
            const float x = sm[pb + j];
            const float y = sm[pb + 21 + j];
            const float z = sm[pb + 42 + j];
            const float u = sm[eb + j];
            const float v = sm[eb + 21 + j];
            const float q0 = fmaf(m00, x, fmaf(m01, y, fmaf(m02, z, -t0)));
            const float q1 = fmaf(m10, x, fmaf(m11, y, fmaf(m12, z, -t1)));
            const float q2 = fmaf(m20, x, fmaf(m21, y, fmaf(m22, z, -t2)));
            const float inv = __builtin_amdgcn_rcpf(q2);   // z ~ 10, safe
            const float du = fmaf(q0, inv, -u);
            const float dv = fmaf(q1, inv, -v);
            const float pt = du * du + dv * dv;
            const bool act = valid && (k < cntq);
            accP += act ? pt : 0.0f;               // select kills garbage/NaN
            const float dx = pvx - x, dy = pvy - y, dz = pvz - z;
            const float sq = dx * dx + dy * dy + dz * dz;
            const float e  = blk[k] - sq;
            accB += (act && j > 0) ? e * e : 0.0f;
            pvx = x; pvy = y; pvz = z;
        }

        T = Tn; ++i;
    }

    // ---- wave reduction + one atomic per block ----
    float acc = WPROJ * accP + WBONE * accB;
    #pragma unroll
    for (int off = 32; off > 0; off >>= 1)
        acc += __shfl_down(acc, off, 64);
    if (tid == 0)
        atomicAdd(out, acc * (1.0f / (float)B));
}

} // namespace

extern "C" void kernel_launch(void* const* d_in, const int* in_sizes, int n_in,
                              void* d_out, int out_size, void* d_ws, size_t ws_size,
                              hipStream_t stream) {
    const float* pose = (const float*)d_in[0];
    const float* est  = (const float*)d_in[1];
    const float* bl   = (const float*)d_in[2];
    const float* Rm   = (const float*)d_in[3];
    const float* Cd   = (const float*)d_in[4];
    float* out = (float*)d_out;

    const int B = in_sizes[0] / 63;               // [B,3,21] flat

    hipMemsetAsync(out, 0, sizeof(float), stream);  // d_out is poisoned 0xAA
    const long ntiles = ((long)B + TILE - 1) / TILE;
    const int  grid   = (int)(ntiles < NBLK ? ntiles : NBLK);
    pose_loss_kernel<<<grid, NT, 0, stream>>>(pose, est, bl, Rm, Cd, out, B);
}